// Round 2
// baseline (314.987 us; speedup 1.0000x reference)
//
#include <hip/hip_runtime.h>

#define BB 32
#define LL 2048
#define DD 128
#define QB 64
#define KB 64
#define NKT (LL / KB)
#define SCALE 0.08838834764831845f
#define DELTA 0.012f
#define CAPA 4096

typedef _Float16 half8 __attribute__((ext_vector_type(8)));
typedef float f4 __attribute__((ext_vector_type(4)));

struct __align__(32) RB { unsigned grow, i1, i2; float p1, p2; unsigned pad[3]; };

// ---------------- main kernel: QK^T via f16 MFMA, online top-3 + sum ----------------
__global__ __launch_bounds__(256)
void attn_main(const float* __restrict__ Q, const float* __restrict__ K,
               const float* __restrict__ V, float* __restrict__ out,
               unsigned* __restrict__ cntA, unsigned* __restrict__ cntB,
               uint2* __restrict__ listA, RB* __restrict__ listB, int capB)
{
    const int blk = blockIdx.x;
    const int b   = blk >> 5;
    const int q0  = (blk & 31) * QB;
    const int tid = threadIdx.x;
    const int wv  = tid >> 6;
    const int lane = tid & 63;

    float* outO = out;
    float* outA = out + (size_t)BB * LL * DD;
    f4* az = (f4*)(outA + (size_t)(b * LL + q0) * LL);   // 32768 f4's to zero

    // Q A-fragments (scaled) held in registers for the whole kernel.
    // A layout (16x16x32): lane holds A[row=lane&15][k=(lane>>4)*8+j]
    half8 qa[4];
    {
        const int qrow = q0 + (wv << 4) + (lane & 15);
        const float* qsrc = Q + ((size_t)b * LL + qrow) * DD + ((lane >> 4) << 3);
#pragma unroll
        for (int db = 0; db < 4; ++db) {
            f4 x = *(const f4*)(qsrc + db * 32);
            f4 y = *(const f4*)(qsrc + db * 32 + 4);
            half8 h;
            h[0]=(_Float16)(x[0]*SCALE); h[1]=(_Float16)(x[1]*SCALE);
            h[2]=(_Float16)(x[2]*SCALE); h[3]=(_Float16)(x[3]*SCALE);
            h[4]=(_Float16)(y[0]*SCALE); h[5]=(_Float16)(y[1]*SCALE);
            h[6]=(_Float16)(y[2]*SCALE); h[7]=(_Float16)(y[3]*SCALE);
            qa[db] = h;
        }
    }

    __shared__ __align__(16) _Float16 Klds[KB * DD];   // 16 KB, fragment-ordered
    __shared__ float p_sh[QB];
    __shared__ int   ix_sh[QB];

    float m1[4], m2[4], m3[4], sm[4];
    int   i1[4], i2[4];
#pragma unroll
    for (int j = 0; j < 4; ++j) { m1[j]=m2[j]=m3[j]=-1e30f; sm[j]=0.f; i1[j]=i2[j]=0; }

    const float* kbat = K + (size_t)b * LL * DD;

    for (int kt = 0; kt < NKT; ++kt) {
        __syncthreads();                       // Klds reuse guard
        // interleaved zeroing of this block's attn rows (1024 f4 per iter)
        {
            f4 z = {0.f,0.f,0.f,0.f};
            int base = kt * 1024 + tid;
            az[base] = z; az[base+256] = z; az[base+512] = z; az[base+768] = z;
        }
        // stage + convert K tile into fragment-ordered LDS
#pragma unroll
        for (int i = 0; i < 4; ++i) {
            int c = tid + i * 256;             // chunk 0..1023
            int sub = c >> 6, ln = c & 63;
            int keyl = ((sub >> 2) << 4) + (ln & 15);
            int d0   = ((sub & 3) << 5) + ((ln >> 4) << 3);
            const float* src = kbat + (size_t)(kt * KB + keyl) * DD + d0;
            f4 x = *(const f4*)src;
            f4 y = *(const f4*)(src + 4);
            half8 h;
            h[0]=(_Float16)x[0]; h[1]=(_Float16)x[1]; h[2]=(_Float16)x[2]; h[3]=(_Float16)x[3];
            h[4]=(_Float16)y[0]; h[5]=(_Float16)y[1]; h[6]=(_Float16)y[2]; h[7]=(_Float16)y[3];
            *(half8*)(Klds + (size_t)c * 8) = h;
        }
        __syncthreads();

#pragma unroll
        for (int kb2 = 0; kb2 < 4; ++kb2) {
            f4 acc = {0.f,0.f,0.f,0.f};
#pragma unroll
            for (int db = 0; db < 4; ++db) {
                half8 bf = *(const half8*)(Klds + ((((kb2 << 2) + db) << 6) + lane) * 8);
                acc = __builtin_amdgcn_mfma_f32_16x16x32_f16(qa[db], bf, acc, 0, 0, 0);
            }
            const int key = kt * KB + (kb2 << 4) + (lane & 15);
#pragma unroll
            for (int j = 0; j < 4; ++j) {
                float s = acc[j];
                if (s > m3[j]) {
                    if (s > m1[j]) {
                        m3[j]=m2[j]; m2[j]=m1[j]; i2[j]=i1[j];
                        sm[j] *= __expf(m1[j] - s);
                        m1[j]=s; i1[j]=key;
                    } else if (s > m2[j]) {
                        m3[j]=m2[j]; m2[j]=s; i2[j]=key;
                    } else m3[j]=s;
                }
                sm[j] += __expf(s - m1[j]);
            }
        }
    }
    __syncthreads();   // drain zero-stores before same-address scatter below

    // cross-lane merge over the 16 lanes holding each row's columns
#pragma unroll
    for (int off = 1; off < 16; off <<= 1) {
#pragma unroll
        for (int j = 0; j < 4; ++j) {
            float om1 = __shfl_xor(m1[j], off);
            float om2 = __shfl_xor(m2[j], off);
            float om3 = __shfl_xor(m3[j], off);
            float osm = __shfl_xor(sm[j], off);
            int   oi1 = __shfl_xor(i1[j], off);
            int   oi2 = __shfl_xor(i2[j], off);
            float Mn = fmaxf(m1[j], om1);
            sm[j] = sm[j]*__expf(m1[j]-Mn) + osm*__expf(om1-Mn);
            if (om1 > m1[j]) {
                float t;  int ti;
                t=m1[j]; m1[j]=om1; om1=t;
                t=m2[j]; m2[j]=om2; om2=t;
                t=m3[j]; m3[j]=om3; om3=t;
                ti=i1[j]; i1[j]=oi1; oi1=ti;
                ti=i2[j]; i2[j]=oi2; oi2=ti;
            }
            if (om1 > m2[j]) { m3[j]=fmaxf(m2[j], om2); m2[j]=om1; i2[j]=oi1; }
            else             { m3[j]=fmaxf(m3[j], om1); }
        }
    }

    if ((lane & 15) == 0) {
#pragma unroll
        for (int j = 0; j < 4; ++j) {
            int r = (wv << 4) + ((lane >> 4) << 2) + j;
            int grow = b * LL + q0 + r;
            float p1 = 1.f / sm[j];
            p_sh[r] = p1; ix_sh[r] = i1[j];
            outA[(size_t)grow * LL + i1[j]] = p1;
            float g13 = m1[j] - m3[j];
            float g12 = m1[j] - m2[j];
            if (g13 <= DELTA) {
                unsigned slot = atomicAdd(cntA, 1u);
                if (slot < CAPA) listA[slot] = make_uint2((unsigned)grow, (unsigned)i1[j]);
            } else if (g12 <= DELTA) {
                unsigned slot = atomicAdd(cntB, 1u);
                if (slot < (unsigned)capB) {
                    RB rb; rb.grow=(unsigned)grow; rb.i1=(unsigned)i1[j]; rb.i2=(unsigned)i2[j];
                    rb.p1=p1; rb.p2=__expf(m2[j]-m1[j])*p1;
                    rb.pad[0]=rb.pad[1]=rb.pad[2]=0;
                    listB[slot] = rb;
                }
            }
        }
    }
    __syncthreads();

    // output rows: thread t -> row t>>2, 32-float segment t&3
    {
        int r = tid >> 2, seg = tid & 3;
        float p = p_sh[r];
        int   ky = ix_sh[r];
        const float* vs = V + ((size_t)b * LL + ky) * DD + seg * 32;
        float* dst = outO + ((size_t)(b * LL + q0 + r)) * DD + seg * 32;
#pragma unroll
        for (int c = 0; c < 32; c += 4) {
            f4 v4 = *(const f4*)(vs + c);
            *(f4*)(dst + c) = v4 * p;
        }
    }
}

// ---------------- fix-up B: two-candidate fp64 compare ----------------
__global__ __launch_bounds__(64)
void fix_pair(const float* __restrict__ Q, const float* __restrict__ K,
              const float* __restrict__ V, float* __restrict__ out,
              const unsigned* __restrict__ cntB, const RB* __restrict__ listB, int capB)
{
    int n = (int)min(*cntB, (unsigned)capB);
    float* outA = out + (size_t)BB * LL * DD;
    int lane = threadIdx.x;
    for (int e = blockIdx.x; e < n; e += gridDim.x) {
        RB r = listB[e];
        int b = (int)(r.grow >> 11);
        const float* q  = Q + (size_t)r.grow * DD;
        const float* k1 = K + ((size_t)(b << 11) + r.i1) * DD;
        const float* k2 = K + ((size_t)(b << 11) + r.i2) * DD;
        double a1 = 0.0, a2 = 0.0;
        for (int d = lane; d < DD; d += 64) {
            double qd = (double)q[d];
            a1 += qd * (double)k1[d];
            a2 += qd * (double)k2[d];
        }
#pragma unroll
        for (int off = 32; off > 0; off >>= 1) {
            a1 += __shfl_down(a1, off);
            a2 += __shfl_down(a2, off);
        }
        int sel = (a2 > a1) ? 1 : 0;
        sel = __shfl(sel, 0);
        if (sel) {
            if (lane == 0) {
                outA[(size_t)r.grow * LL + r.i1] = 0.f;
                outA[(size_t)r.grow * LL + r.i2] = r.p2;
            }
            const float* vs = V + ((size_t)(b << 11) + r.i2) * DD;
            float* dst = out + (size_t)r.grow * DD;
            for (int d = lane; d < DD; d += 64) dst[d] = r.p2 * vs[d];
        }
    }
}

// ---------------- fix-up A: full fp64 row rescan ----------------
__global__ __launch_bounds__(256)
void fix_full(const float* __restrict__ Q, const float* __restrict__ K,
              const float* __restrict__ V, float* __restrict__ out,
              const unsigned* __restrict__ cntA, const uint2* __restrict__ listA)
{
    __shared__ float  qsh[DD];
    __shared__ double rbuf[256];
    __shared__ int    ibuf[256];
    int n = (int)min(*cntA, (unsigned)CAPA);
    float* outA = out + (size_t)BB * LL * DD;
    int tid = threadIdx.x;
    for (int e = blockIdx.x; e < n; e += gridDim.x) {
        uint2 en = listA[e];
        int grow = (int)en.x, iold = (int)en.y;
        int b = grow >> 11;
        __syncthreads();
        if (tid < DD) qsh[tid] = Q[(size_t)grow * DD + tid];
        __syncthreads();
        double ls[8];
        double best = -1e300; int bidx = 0;
#pragma unroll
        for (int kk = 0; kk < 8; ++kk) {
            int key = (kk << 8) + tid;
            const float* kr = K + ((size_t)(b << 11) + key) * DD;
            double acc = 0.0;
            for (int d = 0; d < DD; ++d) acc += (double)qsh[d] * (double)kr[d];
            acc *= (double)SCALE;
            ls[kk] = acc;
            if (acc > best) { best = acc; bidx = key; }
        }
        rbuf[tid] = best; ibuf[tid] = bidx;
        __syncthreads();
        for (int s2 = 128; s2 > 0; s2 >>= 1) {
            if (tid < s2 && rbuf[tid + s2] > rbuf[tid]) { rbuf[tid]=rbuf[tid+s2]; ibuf[tid]=ibuf[tid+s2]; }
            __syncthreads();
        }
        double gbest = rbuf[0]; int gidx = ibuf[0];
        __syncthreads();
        double lsum = 0.0;
#pragma unroll
        for (int kk = 0; kk < 8; ++kk) lsum += exp(ls[kk] - gbest);
        rbuf[tid] = lsum;
        __syncthreads();
        for (int s2 = 128; s2 > 0; s2 >>= 1) {
            if (tid < s2) rbuf[tid] += rbuf[tid + s2];
            __syncthreads();
        }
        float p = (float)(1.0 / rbuf[0]);
        if (tid == 0) {
            outA[(size_t)grow * LL + iold] = 0.f;
            outA[(size_t)grow * LL + gidx] = p;
        }
        if (tid < DD) out[(size_t)grow * DD + tid] = p * V[((size_t)(b << 11) + gidx) * DD + tid];
        __syncthreads();
    }
}

extern "C" void kernel_launch(void* const* d_in, const int* in_sizes, int n_in,
                              void* d_out, int out_size, void* d_ws, size_t ws_size,
                              hipStream_t stream)
{
    const float* Q = (const float*)d_in[0];
    const float* K = (const float*)d_in[1];
    const float* V = (const float*)d_in[2];
    float* out = (float*)d_out;

    unsigned* cntA = (unsigned*)d_ws;
    unsigned* cntB = cntA + 1;
    uint2* listA = (uint2*)((char*)d_ws + 64);
    size_t offB = 64 + (size_t)CAPA * 8;          // 32832, 32B-aligned
    RB* listB = (RB*)((char*)d_ws + offB);
    int capB = 0;
    if (ws_size > offB + 32) capB = (int)((ws_size - offB) / 32);
    if (capB > 65536) capB = 65536;

    hipMemsetAsync(d_ws, 0, 8, stream);           // zero both counters (deterministic)
    hipLaunchKernelGGL(attn_main, dim3(BB * (LL / QB)), dim3(256), 0, stream,
                       Q, K, V, out, cntA, cntB, listA, listB, capB);
    hipLaunchKernelGGL(fix_full, dim3(256), dim3(256), 0, stream, Q, K, V, out, cntA, listA);
    hipLaunchKernelGGL(fix_pair, dim3(2048), dim3(64), 0, stream, Q, K, V, out, cntB, listB, capB);
}